// Round 4
// baseline (354.970 us; speedup 1.0000x reference)
//
#include <hip/hip_runtime.h>

// ---------------------------------------------------------------------------
// CanonicalLinear: out[b,c] = sum_n factor[n] * (x @ W[n]^T + b[n])[b,c]
// Collapse heads: Weff = sum_n factor[n]*W[n] (C x D), beff = sum_n factor[n]*b[n]
// then out = x @ Weff^T + beff  -- bf16 MFMA GEMM (m97 structure).
// Round 6 (this): eliminate the xbf intermediate entirely.
//   R1-R3 evidence: prep stuck at 84-94us across 3 structures (2.6 TB/s
//   effective; not latency, not VALU, not width, not banks) -> stop
//   micro-tuning, delete work instead. x->bf16 now happens inside the
//   GEMM A-staging: load fp32 x, pack via v_cvt_pk_bf16_f32 (T12 recipe,
//   4 instr / 8 floats), ds_write to the SAME swizzled LDS slots
//   global_load_lds used. Saves 96 MB (40%) of prep traffic + instrs.
//   Prep split into named kernels for per-stream counters.
// ---------------------------------------------------------------------------

#define MDIM 8192
#define KDIM 2048
#define NDIM 2048
#define NHEADS 8

#define BM 128
#define BN 128
#define BK 64

#define WBLKS 1024
#define BBLKS 8

using bf16x8 = __attribute__((ext_vector_type(8))) short;
using f32x4  = __attribute__((ext_vector_type(4))) float;
using f4v    = __attribute__((ext_vector_type(4))) float;
using u16x8  = __attribute__((ext_vector_type(8))) unsigned short;

__device__ __forceinline__ unsigned short f2bf(float x) {
    unsigned int u = __float_as_uint(x);
    u += 0x7FFFu + ((u >> 16) & 1u);
    return (unsigned short)(u >> 16);
}

// 2 fp32 -> packed 2x bf16 (RNE), single instruction. T12 (m214v22) recipe.
__device__ __forceinline__ unsigned int cvt_pk_bf16(float lo, float hi) {
    unsigned int r;
    asm("v_cvt_pk_bf16_f32 %0, %1, %2" : "=v"(r) : "v"(lo), "v"(hi));
    return r;
}

__device__ __forceinline__ void async_load16(const void* g, void* l) {
    __builtin_amdgcn_global_load_lds(
        (const __attribute__((address_space(1))) unsigned int*)g,
        (__attribute__((address_space(3))) unsigned int*)l,
        16, 0, 0);
}

// --- prep_w: Wbf[i..i+8) = bf16(sum_n f[n]*W[n][i..i+8))  (16B stores) ------
__global__ __launch_bounds__(256) void prep_w_kernel(
        const float* __restrict__ W,
        const float* __restrict__ factor,
        unsigned short* __restrict__ Wbf) {
    const size_t CD      = (size_t)NDIM * KDIM;          // 4,194,304 floats/head
    const size_t tbase   = ((size_t)blockIdx.x * 256 + threadIdx.x) * 8;
    const size_t gstride = (size_t)WBLKS * 256 * 8;      // 2,097,152 floats
    float f[NHEADS];
#pragma unroll
    for (int n = 0; n < NHEADS; ++n) f[n] = factor[n];
#pragma unroll
    for (int g = 0; g < 2; ++g) {
        const size_t i = tbase + (size_t)g * gstride;
        f4v v0[NHEADS], v1[NHEADS];
#pragma unroll
        for (int n = 0; n < NHEADS; ++n) {
            const float* p = W + (size_t)n * CD + i;
            v0[n] = *reinterpret_cast<const f4v*>(p);
            v1[n] = *reinterpret_cast<const f4v*>(p + 4);
        }
        float a0 = 0.f, a1 = 0.f, a2 = 0.f, a3 = 0.f;
        float a4 = 0.f, a5 = 0.f, a6 = 0.f, a7 = 0.f;
#pragma unroll
        for (int n = 0; n < NHEADS; ++n) {
            a0 += f[n] * v0[n].x; a1 += f[n] * v0[n].y;
            a2 += f[n] * v0[n].z; a3 += f[n] * v0[n].w;
            a4 += f[n] * v1[n].x; a5 += f[n] * v1[n].y;
            a6 += f[n] * v1[n].z; a7 += f[n] * v1[n].w;
        }
        u16x8 o;
        o[0] = f2bf(a0); o[1] = f2bf(a1); o[2] = f2bf(a2); o[3] = f2bf(a3);
        o[4] = f2bf(a4); o[5] = f2bf(a5); o[6] = f2bf(a6); o[7] = f2bf(a7);
        *reinterpret_cast<u16x8*>(Wbf + i) = o;
    }
}

// --- prep_bias: beff[c] = sum_n f[n]*b[n,c] ---------------------------------
__global__ __launch_bounds__(256) void prep_bias_kernel(
        const float* __restrict__ b,
        const float* __restrict__ factor,
        float* __restrict__ beff) {
    int c = blockIdx.x * 256 + threadIdx.x;
    float s = 0.f;
#pragma unroll
    for (int n = 0; n < NHEADS; ++n) s += factor[n] * b[(size_t)n * NDIM + c];
    beff[c] = s;
}

// --- GEMM: out[m,c] = sum_k x[m,k]*B[c,k] + bias[c] -------------------------
// A-path: reg-staged from fp32 x with in-flight bf16 pack (cvt_pk).
// B-path: global_load_lds from Wbf (unchanged). LDS layout/read unchanged.
__global__ __launch_bounds__(256) void gemm_bt_kernel(
    const float* __restrict__ X,            // x    [MDIM][KDIM] fp32
    const unsigned short* __restrict__ B,   // Wbf  [NDIM][KDIM] bf16
    const float* __restrict__ bias,         // beff [NDIM]
    float* __restrict__ C)                  // out  [MDIM][NDIM] fp32
{
    __shared__ unsigned short As[BM * BK];  // 16 KB
    __shared__ unsigned short Bs[BN * BK];  // 16 KB

    const int tid  = threadIdx.x;
    const int lane = tid & 63;
    const int w    = tid >> 6;      // wave 0..3
    const int m16  = lane & 15;
    const int quad = lane >> 4;     // 0..3

    // XCD-aware swizzle: xcd = bid&7 owns N-tiles {2*xcd, 2*xcd+1}.
    const int bid = blockIdx.x;
    const int g   = bid >> 3;
    const int nt  = (bid & 7) * 2 + (g & 1);
    const int mt  = g >> 1;
    const int blockN0 = nt * BN;
    const int blockM0 = mt * BM;

    const int wr = (w >> 1) * 64;   // wave's row quadrant in tile
    const int wc = (w & 1) * 64;    // wave's col quadrant

    // staging geometry (identical LDS image to the global_load_lds version):
    // lane writes 16 B at row (r + lane>>3), col-group (lane&7); the GLOBAL
    // column group is pre-XOR-swizzled by row&7.
    const int srow = lane >> 3;                    // 0..7
    const int scol = ((lane & 7) ^ srow) * 8;      // swizzled global elem col
    const float*          xP[4];
    const unsigned short* bP[4];
    unsigned short*       aW[4];
    unsigned short*       bL[4];
#pragma unroll
    for (int i = 0; i < 4; ++i) {
        int r = i * 32 + w * 8;
        xP[i] = X + (size_t)(blockM0 + r + srow) * KDIM + scol;
        bP[i] = B + (size_t)(blockN0 + r + srow) * KDIM + scol;
        aW[i] = As + (size_t)r * BK + lane * 8;    // per-lane ds_write target
        bL[i] = Bs + (size_t)r * BK;               // wave-uniform LDS base
    }

    f32x4 acc[4][4] = {};

    for (int k0 = 0; k0 < KDIM; k0 += BK) {
        // B: async global->LDS (16 B widths)
#pragma unroll
        for (int i = 0; i < 4; ++i) {
            async_load16(bP[i], bL[i]);
            bP[i] += BK;
        }
        // A: fp32 load -> cvt_pk bf16 -> ds_write_b128 (same slots as before)
#pragma unroll
        for (int i = 0; i < 4; ++i) {
            f4v v0 = *reinterpret_cast<const f4v*>(xP[i]);
            f4v v1 = *reinterpret_cast<const f4v*>(xP[i] + 4);
            xP[i] += BK;
            uint4 o;
            o.x = cvt_pk_bf16(v0.x, v0.y);
            o.y = cvt_pk_bf16(v0.z, v0.w);
            o.z = cvt_pk_bf16(v1.x, v1.y);
            o.w = cvt_pk_bf16(v1.z, v1.w);
            *reinterpret_cast<uint4*>(aW[i]) = o;
        }
        __syncthreads();

#pragma unroll
        for (int kk = 0; kk < BK; kk += 32) {
            bf16x8 af[4], bfr[4];
#pragma unroll
            for (int rt = 0; rt < 4; ++rt) {
                int row = wr + rt * 16 + m16;
                int gA = ((kk >> 3) + quad) ^ (row & 7);   // un-swizzle
                af[rt] = *reinterpret_cast<const bf16x8*>(&As[(size_t)row * BK + gA * 8]);
            }
#pragma unroll
            for (int ct = 0; ct < 4; ++ct) {
                int row = wc + ct * 16 + m16;
                int gB = ((kk >> 3) + quad) ^ (row & 7);
                bfr[ct] = *reinterpret_cast<const bf16x8*>(&Bs[(size_t)row * BK + gB * 8]);
            }
#pragma unroll
            for (int rt = 0; rt < 4; ++rt)
#pragma unroll
                for (int ct = 0; ct < 4; ++ct)
                    acc[rt][ct] = __builtin_amdgcn_mfma_f32_16x16x32_bf16(
                        af[rt], bfr[ct], acc[rt][ct], 0, 0, 0);
        }
        __syncthreads();
    }

    // epilogue: C/D layout col=lane&15, row=quad*4+reg (verified m89/m91)
    float bv[4];
#pragma unroll
    for (int ct = 0; ct < 4; ++ct) bv[ct] = bias[blockN0 + wc + ct * 16 + m16];
#pragma unroll
    for (int rt = 0; rt < 4; ++rt) {
        int row0 = blockM0 + wr + rt * 16 + quad * 4;
#pragma unroll
        for (int ct = 0; ct < 4; ++ct) {
            int col = blockN0 + wc + ct * 16 + m16;
#pragma unroll
            for (int r = 0; r < 4; ++r)
                C[(size_t)(row0 + r) * NDIM + col] = acc[rt][ct][r] + bv[ct];
        }
    }
}

extern "C" void kernel_launch(void* const* d_in, const int* in_sizes, int n_in,
                              void* d_out, int out_size, void* d_ws, size_t ws_size,
                              hipStream_t stream) {
    const float* x      = (const float*)d_in[0];   // [8192][2048]
    const float* W      = (const float*)d_in[1];   // [8][2048][2048]
    const float* b      = (const float*)d_in[2];   // [8][2048]
    const float* factor = (const float*)d_in[3];   // [8]
    float* out = (float*)d_out;                    // [8192][2048]

    unsigned short* Wbf  = (unsigned short*)d_ws;                      // 8,388,608 B
    float*          beff = (float*)((char*)d_ws + 8388608);            //     8,192 B

    prep_w_kernel<<<dim3(WBLKS), dim3(256), 0, stream>>>(W, factor, Wbf);
    prep_bias_kernel<<<dim3(BBLKS), dim3(256), 0, stream>>>(b, factor, beff);
    gemm_bt_kernel<<<dim3(1024), dim3(256), 0, stream>>>(x, Wbf, beff, out);
}

// Round 5
// 340.701 us; speedup vs baseline: 1.0419x; 1.0419x over previous
//
#include <hip/hip_runtime.h>

// ---------------------------------------------------------------------------
// CanonicalLinear: out[b,c] = sum_n factor[n] * (x @ W[n]^T + b[n])[b,c]
// Weff = sum_n f[n]*W[n]; beff = sum_n f[n]*b[n]; out = x @ Weff^T + beff.
// Round 7: REVERT R4 fusion (fp32-A doubled FETCH 139->270 MB, gemm 85->137).
//   Back to R2 prep (xbf+Wbf, best measured ~84-90us).
//   GEMM: new counted-vmcnt 3-slot LDS ring (T4 mechanism, race-free by
//   construction): 256x128 tile, 8 waves, BK=64, LDS 3x48KB=144KB.
//   stage(t+2) -> slot[(t+2)%3] issued during compute(t); that slot was
//   consumed at end of compute(t-1), a full barrier generation earlier.
//   vmcnt(6) steady state (stage(t) landed, stage(t+1) in flight), vmcnt(0)
//   only at the last K-tile. One barrier per K-tile (was two). Swizzle,
//   fragment math, epilogue layout unchanged from verified kernel.
// ---------------------------------------------------------------------------

#define MDIM 8192
#define KDIM 2048
#define NDIM 2048
#define NHEADS 8

#define BM 256
#define BN 128
#define BK 64
#define NT (KDIM / BK)          // 32 K-tiles
#define ABUF_ELEMS (BM * BK)    // 16384 bf16 = 32 KB
#define BBUF_ELEMS (BN * BK)    //  8192 bf16 = 16 KB

// prep geometry (R2 verbatim)
#define WBLKS 1024
#define XBLKS 1024
#define BBLKS 8

using bf16x8 = __attribute__((ext_vector_type(8))) short;
using f32x4  = __attribute__((ext_vector_type(4))) float;
using f4v    = __attribute__((ext_vector_type(4))) float;

__device__ __forceinline__ unsigned short f2bf(float x) {
    unsigned int u = __float_as_uint(x);
    u += 0x7FFFu + ((u >> 16) & 1u);
    return (unsigned short)(u >> 16);
}

__device__ __forceinline__ void async_load16(const void* g, void* l) {
    __builtin_amdgcn_global_load_lds(
        (const __attribute__((address_space(1))) unsigned int*)g,
        (__attribute__((address_space(3))) unsigned int*)l,
        16, 0, 0);
}

// --- fused prep (R2 verbatim: best measured variant) ------------------------
__global__ __launch_bounds__(256) void prep_kernel(
        const float* __restrict__ x,
        const float* __restrict__ W,
        const float* __restrict__ b,
        const float* __restrict__ factor,
        unsigned short* __restrict__ xbf,
        unsigned short* __restrict__ Wbf,
        float* __restrict__ beff) {
    const int blk = blockIdx.x;
    const int tid = threadIdx.x;
    if (blk < WBLKS) {
        const size_t CD   = (size_t)NDIM * KDIM;
        const int    nthr = WBLKS * 256;
        const int    c0   = blk * 256 + tid;
        float f[NHEADS];
#pragma unroll
        for (int n = 0; n < NHEADS; ++n) f[n] = factor[n];
        f4v v[4][NHEADS];
#pragma unroll
        for (int it = 0; it < 4; ++it) {
            size_t idx = ((size_t)(c0 + it * nthr)) * 4;
#pragma unroll
            for (int n = 0; n < NHEADS; ++n)
                v[it][n] = *reinterpret_cast<const f4v*>(W + (size_t)n * CD + idx);
        }
#pragma unroll
        for (int it = 0; it < 4; ++it) {
            size_t idx = ((size_t)(c0 + it * nthr)) * 4;
            float ax = 0.f, ay = 0.f, az = 0.f, aw = 0.f;
#pragma unroll
            for (int n = 0; n < NHEADS; ++n) {
                ax += f[n] * v[it][n].x; ay += f[n] * v[it][n].y;
                az += f[n] * v[it][n].z; aw += f[n] * v[it][n].w;
            }
            ushort4 o;
            o.x = f2bf(ax); o.y = f2bf(ay); o.z = f2bf(az); o.w = f2bf(aw);
            *reinterpret_cast<ushort4*>(Wbf + idx) = o;
        }
    } else if (blk < WBLKS + XBLKS) {
        const int nthr = XBLKS * 256;
        const int c0   = (blk - WBLKS) * 256 + tid;
#pragma unroll
        for (int it = 0; it < 16; it += 4) {
            f4v v[4];
#pragma unroll
            for (int j = 0; j < 4; ++j)
                v[j] = *reinterpret_cast<const f4v*>(
                    x + ((size_t)(c0 + (it + j) * nthr)) * 4);
#pragma unroll
            for (int j = 0; j < 4; ++j) {
                size_t idx = ((size_t)(c0 + (it + j) * nthr)) * 4;
                ushort4 o;
                o.x = f2bf(v[j].x); o.y = f2bf(v[j].y);
                o.z = f2bf(v[j].z); o.w = f2bf(v[j].w);
                *reinterpret_cast<ushort4*>(xbf + idx) = o;
            }
        }
    } else {
        int c = (blk - WBLKS - XBLKS) * 256 + tid;
        float s = 0.f;
#pragma unroll
        for (int n = 0; n < NHEADS; ++n) s += factor[n] * b[(size_t)n * NDIM + c];
        beff[c] = s;
    }
}

// --- GEMM: out[m,c] = sum_k A[m,k]*B[c,k] + bias[c]  (B^T layout) -----------
// 256x128 tile, 8 waves (512 thr), counted-vmcnt 3-slot LDS ring.
__global__ __launch_bounds__(512) void gemm_bt_kernel(
    const unsigned short* __restrict__ A,   // xbf  [MDIM][KDIM]
    const unsigned short* __restrict__ B,   // Wbf  [NDIM][KDIM]
    const float* __restrict__ bias,         // beff [NDIM]
    float* __restrict__ C)                  // out  [MDIM][NDIM] fp32
{
    __shared__ unsigned short ring[3][ABUF_ELEMS + BBUF_ELEMS];  // 144 KB

    const int tid  = threadIdx.x;
    const int lane = tid & 63;
    const int w    = tid >> 6;      // wave 0..7
    const int m16  = lane & 15;
    const int quad = lane >> 4;     // 0..3
    const int wm   = w >> 2;        // 0..1: wave's 128-row half of BM
    const int wn   = w & 3;         // 0..3: wave's 32-col slice of BN

    // XCD-aware bijective swizzle: 512 blocks = 8 xcd * 64; xcd owns 2 nt.
    const int bid = blockIdx.x;
    const int g   = bid >> 3;                 // 0..63
    const int nt  = (bid & 7) * 2 + (g & 1);  // 0..15
    const int mt  = g >> 1;                   // 0..31
    const int blockN0 = nt * BN;
    const int blockM0 = mt * BM;

    // staging: per K-tile, thread issues 4 A-loads + 2 B-loads of 16 B.
    // Wave-issue i covers 8 rows (1 KB); lane l -> row +(l>>3), group (l&7).
    // Global col-group pre-XOR-swizzled by row&7 (same scheme as verified).
    const int srow = lane >> 3;                 // 0..7
    const int scol = ((lane & 7) ^ srow) * 8;   // swizzled global bf16 col
    const unsigned short* aP[4];
    const unsigned short* bP[2];
#pragma unroll
    for (int i = 0; i < 4; ++i)
        aP[i] = A + (size_t)(blockM0 + (i * 8 + w) * 8 + srow) * KDIM + scol;
#pragma unroll
    for (int j = 0; j < 2; ++j)
        bP[j] = B + (size_t)(blockN0 + (j * 8 + w) * 8 + srow) * KDIM + scol;

    // prologue: stage K-tiles 0,1 into slots 0,1 (12 loads/thread in flight)
#pragma unroll
    for (int tt = 0; tt < 2; ++tt) {
        unsigned short* As_r = &ring[tt][0];
        unsigned short* Bs_r = &ring[tt][ABUF_ELEMS];
        const size_t kofs = (size_t)tt * BK;
#pragma unroll
        for (int i = 0; i < 4; ++i)
            async_load16(aP[i] + kofs, As_r + (i * 8 + w) * 512);
#pragma unroll
        for (int j = 0; j < 2; ++j)
            async_load16(bP[j] + kofs, Bs_r + (j * 8 + w) * 512);
    }

    f32x4 acc[8][2] = {};

    for (int t = 0; t < NT; ++t) {
        // stage(t) landed iff all but the newest 6 loads (stage(t+1)) are done.
        if (t == NT - 1) asm volatile("s_waitcnt vmcnt(0)" ::: "memory");
        else             asm volatile("s_waitcnt vmcnt(6)" ::: "memory");
        __builtin_amdgcn_s_barrier();
        __builtin_amdgcn_sched_barrier(0);

        // issue stage(t+2) into slot[(t+2)%3] -- that slot was consumed at the
        // end of compute(t-1), a full barrier generation ago: race-free.
        if (t + 2 < NT) {
            const int s2 = (t + 2) % 3;
            unsigned short* As_r = &ring[s2][0];
            unsigned short* Bs_r = &ring[s2][ABUF_ELEMS];
            const size_t kofs = (size_t)(t + 2) * BK;
#pragma unroll
            for (int i = 0; i < 4; ++i)
                async_load16(aP[i] + kofs, As_r + (i * 8 + w) * 512);
#pragma unroll
            for (int j = 0; j < 2; ++j)
                async_load16(bP[j] + kofs, Bs_r + (j * 8 + w) * 512);
        }
        __builtin_amdgcn_sched_barrier(0);

        // compute K-tile t from slot[t%3]
        const int s = t % 3;
        const unsigned short* As_r = &ring[s][0];
        const unsigned short* Bs_r = &ring[s][ABUF_ELEMS];
#pragma unroll
        for (int ks = 0; ks < 2; ++ks) {
            const int G = ks * 4 + quad;        // global k-group this lane reads
            bf16x8 af[8], bfr[2];
#pragma unroll
            for (int rt = 0; rt < 8; ++rt) {
                int row = wm * 128 + rt * 16 + m16;
                int gA = G ^ (row & 7);         // un-swizzle
                af[rt] = *reinterpret_cast<const bf16x8*>(&As_r[(size_t)row * BK + gA * 8]);
            }
#pragma unroll
            for (int ct = 0; ct < 2; ++ct) {
                int row = wn * 32 + ct * 16 + m16;
                int gB = G ^ (row & 7);
                bfr[ct] = *reinterpret_cast<const bf16x8*>(&Bs_r[(size_t)row * BK + gB * 8]);
            }
#pragma unroll
            for (int rt = 0; rt < 8; ++rt)
#pragma unroll
                for (int ct = 0; ct < 2; ++ct)
                    acc[rt][ct] = __builtin_amdgcn_mfma_f32_16x16x32_bf16(
                        af[rt], bfr[ct], acc[rt][ct], 0, 0, 0);
        }
        // no trailing barrier: next iteration's wait+barrier covers reuse.
    }

    // epilogue: C/D layout col=lane&15, row=quad*4+reg (verified m89/m91)
    float bv[2];
#pragma unroll
    for (int ct = 0; ct < 2; ++ct) bv[ct] = bias[blockN0 + wn * 32 + ct * 16 + m16];
#pragma unroll
    for (int rt = 0; rt < 8; ++rt) {
        int row0 = blockM0 + wm * 128 + rt * 16 + quad * 4;
#pragma unroll
        for (int ct = 0; ct < 2; ++ct) {
            int col = blockN0 + wn * 32 + ct * 16 + m16;
#pragma unroll
            for (int r = 0; r < 4; ++r)
                C[(size_t)(row0 + r) * NDIM + col] = acc[rt][ct][r] + bv[ct];
        }
    }
}

extern "C" void kernel_launch(void* const* d_in, const int* in_sizes, int n_in,
                              void* d_out, int out_size, void* d_ws, size_t ws_size,
                              hipStream_t stream) {
    const float* x      = (const float*)d_in[0];   // [8192][2048]
    const float* W      = (const float*)d_in[1];   // [8][2048][2048]
    const float* b      = (const float*)d_in[2];   // [8][2048]
    const float* factor = (const float*)d_in[3];   // [8]
    float* out = (float*)d_out;                    // [8192][2048]

    unsigned short* xbf  = (unsigned short*)d_ws;                         // 33,554,432 B
    unsigned short* Wbf  = (unsigned short*)((char*)d_ws + 33554432);     //  8,388,608 B
    float*          beff = (float*)((char*)d_ws + 33554432 + 8388608);    //      8,192 B

    prep_kernel<<<dim3(WBLKS + XBLKS + BBLKS), dim3(256), 0, stream>>>(
        x, W, b, factor, xbf, Wbf, beff);
    gemm_bt_kernel<<<dim3(512), dim3(512), 0, stream>>>(xbf, Wbf, beff, out);
}